// Round 15
// baseline (478.934 us; speedup 1.0000x reference)
//
#include <hip/hip_runtime.h>
#include <stdint.h>

#define B_ROWS 4096
#define L_FEAT 256
#define VOCAB  8192
#define NW     (VOCAB / 32)     // 256 words per row bitmap
#define NG     (B_ROWS / 32)    // 128 row-groups
// bits layout: [g][w][i] u32  (g<128, w<256, i<32)  -> 4 MB, L2-resident

typedef __attribute__((ext_vector_type(4))) float floatx4;

// ---------------- kernel 1: 1-bit presence bitmaps + sizes -------------------
// One block per 32-row group: LDS bitmap (atomicOr scatter), then write the
// [w][i]-transposed group (coalesced uint4: thread t -> addr t*16) + popcount
// row sizes. rw padded [32][257] so the transpose gather (4 reads stride 1028B)
// spreads banks.
__global__ __launch_bounds__(256) void presence_kernel(
    const int* __restrict__ f,
    uint32_t* __restrict__ bits,
    float* __restrict__ sizes) {
  __shared__ uint32_t rw[32][257];     // 32.1 KB
  const int g = blockIdx.x;            // 128 blocks
  const int tid = threadIdx.x;

  for (int j = tid; j < 32 * 257; j += 256) ((uint32_t*)rw)[j] = 0u;
  __syncthreads();

  #pragma unroll
  for (int r = 0; r < 32; ++r) {
    const int v = f[(g * 32 + r) * L_FEAT + tid];   // coalesced
    atomicOr(&rw[r][v >> 5], 1u << (v & 31));       // dups benign
  }
  __syncthreads();

  // transposed write: bits[g][w][i]; thread t -> (w = t>>3 + 32*it, iq = t&7)
  // dst byte addr = w*128 + iq*16 = t*16 + it*4096 -> fully coalesced uint4.
  uint32_t* og = bits + g * (NW * 32);
  const int iq = tid & 7;
  #pragma unroll
  for (int it = 0; it < 8; ++it) {
    const int w = (tid >> 3) + it * 32;
    uint4 val;
    val.x = rw[iq * 4 + 0][w];
    val.y = rw[iq * 4 + 1][w];
    val.z = rw[iq * 4 + 2][w];
    val.w = rw[iq * 4 + 3][w];
    *(uint4*)(og + w * 32 + iq * 4) = val;
  }

  // sizes: wave wv handles rows wv*8..+7
  const int wv = tid >> 6, lane = tid & 63;
  for (int rr = 0; rr < 8; ++rr) {
    const int r = wv * 8 + rr;
    int c = __popc(rw[r][lane]) + __popc(rw[r][lane + 64]) +
            __popc(rw[r][lane + 128]) + __popc(rw[r][lane + 192]);
    #pragma unroll
    for (int off = 32; off > 0; off >>= 1) c += __shfl_down(c, off);
    if (lane == 0) sizes[g * 32 + r] = (float)c;
  }
}

// ---------------- kernel 2: inter = popcount(AND) + Jaccard + mirror ---------
// Round-15: the MFMA path is fabric-bound at ~11 TB/s on >= 16 MB operand
// footprints (invariant across r3/r10/r11/r12/r14). 1-bit bitmaps are 4 MB
// (L2-resident everywhere) and intersection = popc(and): pure VALU,
// v_bcnt_u32_b32 fuses popcount+accumulate. Floor ~55 us.
//   * wave = 32i x 64j tile; lane owns column j; acc[32] in registers.
//   * i-bits: wave-uniform loads of bits[gi][w][0..31] -> s_load + SGPR
//     broadcast into v_and (1 SGPR operand per VALU instr: legal).
//   * j-bits: bits[gj][w][j&31] -> per-lane dword, 2x128B segments per instr.
//   * NO LDS, NO barriers; mirror is free: lane j holds its whole column ->
//     writes 128 B contiguous to out row j (8 x float4).
//   * union >= 1 always (rows non-empty) -> no zero guard needed.
// grid: triangle over (ib<32 of 128 rows, jb in [2*ib, 64)) = 1056 blocks;
// 4 waves/block, each wave one 32-row subgroup. ~5 blocks/CU -> all resident.
__global__ __launch_bounds__(256) void inter_kernel(
    const uint32_t* __restrict__ bits,
    const float* __restrict__ sizes,
    float* __restrict__ out) {
  // triangle decode: row-strip ib (128 rows), col-tile jb (64 cols), jb >= 2*ib
  int b = blockIdx.x, ib = 0, rem = 64;
  while (b >= rem) { b -= rem; ++ib; rem -= 2; }
  const int jb = 2 * ib + b;

  const int tid = threadIdx.x, wave = tid >> 6, lane = tid & 63;
  const int gi = ib * 4 + wave;            // this wave's 32-row i-group
  const int j  = jb * 64 + lane;           // this lane's column

  const uint32_t* __restrict__ ibp = bits + (size_t)gi * (NW * 32);
  const uint32_t* __restrict__ jbp =
      bits + (size_t)((jb << 1) + (lane >> 5)) * (NW * 32) + (lane & 31);

  uint32_t acc[32];
  #pragma unroll
  for (int ii = 0; ii < 32; ++ii) acc[ii] = 0u;

  for (int w = 0; w < NW; ++w) {
    const uint32_t vj = jbp[w * 32];       // per-lane j-word (coalesced)
    const uint32_t* iw = ibp + w * 32;     // wave-uniform -> scalar loads
    #pragma unroll
    for (int ii = 0; ii < 32; ++ii)
      acc[ii] += __popc(vj & iw[ii]);      // v_and + v_bcnt(.., acc)
  }

  // epilogue: sim = -inter/(si+sj-inter); direct (row i) + mirror (row j).
  const float sj = sizes[j];
  const int ibase = gi * 32;
  float sims[32];
  #pragma unroll
  for (int ii = 0; ii < 32; ++ii) {
    const float inter = (float)acc[ii];
    const float si = sizes[ibase + ii];    // uniform -> SGPR
    sims[ii] = -inter / (si + sj - inter); // union >= 1 always
    __builtin_nontemporal_store(sims[ii],
        &out[(size_t)(ibase + ii) * B_ROWS + j]);   // coalesced row-i write
  }
  // mirror: this lane's 32 sims are contiguous in out row j (128 B)
  float* mrow = &out[(size_t)j * B_ROWS + ibase];
  #pragma unroll
  for (int q = 0; q < 8; ++q) {
    floatx4 v4;
    v4[0] = sims[q * 4 + 0]; v4[1] = sims[q * 4 + 1];
    v4[2] = sims[q * 4 + 2]; v4[3] = sims[q * 4 + 3];
    __builtin_nontemporal_store(v4, (floatx4*)(mrow + q * 4));
  }
}

// ---------------- launcher ---------------------------------------------------
extern "C" void kernel_launch(void* const* d_in, const int* in_sizes, int n_in,
                              void* d_out, int out_size, void* d_ws, size_t ws_size,
                              hipStream_t stream) {
  const int* features = (const int*)d_in[0];
  float* out = (float*)d_out;
  uint32_t* bits = (uint32_t*)d_ws;                       // 4 MB bitmaps
  float* sizes = (float*)((char*)d_ws + (size_t)NG * NW * 32 * 4);  // +16 KB

  presence_kernel<<<NG, 256, 0, stream>>>(features, bits, sizes);
  inter_kernel<<<1056, 256, 0, stream>>>(bits, sizes, out);
}

// Round 16
// 286.836 us; speedup vs baseline: 1.6697x; 1.6697x over previous
//
#include <hip/hip_runtime.h>
#include <stdint.h>

#define B_ROWS 4096
#define L_FEAT 256
#define VOCAB  8192
#define NW     (VOCAB / 32)     // 256 words per row bitmap
#define NG     (B_ROWS / 32)    // 128 row-groups
// bits2 layout: [w][row] u32  (w<256, row<4096) -> 4 MB, L2-resident.
// Word-major so 8 consecutive ROWS at one w = 32 B contiguous (one uint4 pair).

typedef __attribute__((ext_vector_type(4))) float floatx4;

// ---------------- kernel 1: 1-bit presence bitmaps (word-major) + sizes ------
// One block per 32-row group: LDS bitmap (atomicOr scatter, verified r15),
// then write the [w][row] layout + popcount row sizes.
__global__ __launch_bounds__(256) void presence_kernel(
    const int* __restrict__ f,
    uint32_t* __restrict__ bits2,
    float* __restrict__ sizes) {
  __shared__ uint32_t rw[32][257];     // padded: transpose gather spreads banks
  const int g = blockIdx.x;            // 128 blocks
  const int tid = threadIdx.x;

  for (int j = tid; j < 32 * 257; j += 256) ((uint32_t*)rw)[j] = 0u;
  __syncthreads();

  #pragma unroll
  for (int r = 0; r < 32; ++r) {
    const int v = f[(g * 32 + r) * L_FEAT + tid];   // coalesced
    atomicOr(&rw[r][v >> 5], 1u << (v & 31));       // dups benign
  }
  __syncthreads();

  // word-major write: bits2[w][g*32 + q*4 .. +3]; thread t -> w = t>>3 + 32*it,
  // q = t&3-ish (8 uint4 per 32-row stripe). 128 B contiguous per w.
  const int q = tid & 7;
  #pragma unroll
  for (int it = 0; it < 8; ++it) {
    const int w = (tid >> 3) + it * 32;
    uint4 val;
    val.x = rw[q * 4 + 0][w];
    val.y = rw[q * 4 + 1][w];
    val.z = rw[q * 4 + 2][w];
    val.w = rw[q * 4 + 3][w];
    *(uint4*)(bits2 + (size_t)w * B_ROWS + g * 32 + q * 4) = val;
  }

  // sizes: wave wv handles rows wv*8..+7 (verified r15)
  const int wv = tid >> 6, lane = tid & 63;
  for (int rr = 0; rr < 8; ++rr) {
    const int r = wv * 8 + rr;
    int c = __popc(rw[r][lane]) + __popc(rw[r][lane + 64]) +
            __popc(rw[r][lane + 128]) + __popc(rw[r][lane + 192]);
    #pragma unroll
    for (int off = 32; off > 0; off >>= 1) c += __shfl_down(c, off);
    if (lane == 0) sizes[g * 32 + r] = (float)c;
  }
}

// ---------------- kernel 2: inter = popcount(AND), 8x8 register tiles --------
// Round-16 fix of r15's two failures:
//   (1) 33 vector loads per w-step -> now 4 uint4 loads per w-step (word-major
//       layout: lane's 8 rows = 32 B contiguous; 8-way lane sharing, 2-4
//       lines/instr). load:VALU = 3%.
//   (2) acc spill (VGPR=32) -> classic register blocking: lane owns an 8x8
//       output tile, acc[8][8] statically indexed, ~100 VGPR, no scratch.
// Wave = 64x64 tile (lane grid 8x8); block = 128x128 (2x2 waves); 528-block
// triangle grid + XCD swizzle. No LDS, no barriers. VALU floor ~56 us
// (69M wave-instrs x 2cyc / 1024 SIMDs); v_bcnt_u32_b32 fuses popc+add.
// Mirror free: lane holds the full 8x8 -> 2 float4 stores per row, both
// orientations. Diagonal blocks double-write identical values (benign).
__global__ __launch_bounds__(256) void inter_kernel(
    const uint32_t* __restrict__ bits2,
    const float* __restrict__ sizes,
    float* __restrict__ out) {
  // XCD swizzle (528 = 8*66 -> bijective) then triangle decode, bx >= by
  int bid = blockIdx.x;
  bid = (bid & 7) * 66 + (bid >> 3);
  int b = bid, by = 0, rem = 32;
  while (b >= rem) { b -= rem; ++by; --rem; }
  const int bx = by + b;

  const int tid = threadIdx.x, wave = tid >> 6, lane = tid & 63;
  const int wm = wave >> 1, wn = wave & 1;
  const int li = lane >> 3, lj = lane & 7;

  const int i0 = by * 128 + wm * 64 + li * 8;   // lane's 8 i-rows
  const int j0 = bx * 128 + wn * 64 + lj * 8;   // lane's 8 j-rows

  const uint32_t* __restrict__ pi = bits2 + i0;
  const uint32_t* __restrict__ pj = bits2 + j0;

  uint32_t acc[8][8];
  #pragma unroll
  for (int r = 0; r < 8; ++r)
    #pragma unroll
    for (int c = 0; c < 8; ++c) acc[r][c] = 0u;

  for (int w = 0; w < NW; ++w) {
    const uint4 ia = *(const uint4*)(pi);
    const uint4 ib = *(const uint4*)(pi + 4);
    const uint4 ja = *(const uint4*)(pj);
    const uint4 jb = *(const uint4*)(pj + 4);
    const uint32_t iw[8] = {ia.x, ia.y, ia.z, ia.w, ib.x, ib.y, ib.z, ib.w};
    const uint32_t jw[8] = {ja.x, ja.y, ja.z, ja.w, jb.x, jb.y, jb.z, jb.w};
    #pragma unroll
    for (int r = 0; r < 8; ++r)
      #pragma unroll
      for (int c = 0; c < 8; ++c)
        acc[r][c] += __popc(iw[r] & jw[c]);   // v_and + v_bcnt_u32_b32
    pi += B_ROWS;
    pj += B_ROWS;
  }

  // epilogue: sim = -inter/(si+sj-inter); union >= 1 always (rows non-empty).
  float si[8], sj[8];
  *(floatx4*)&si[0] = *(const floatx4*)&sizes[i0];
  *(floatx4*)&si[4] = *(const floatx4*)&sizes[i0 + 4];
  *(floatx4*)&sj[0] = *(const floatx4*)&sizes[j0];
  *(floatx4*)&sj[4] = *(const floatx4*)&sizes[j0 + 4];

  float sims[8][8];
  #pragma unroll
  for (int r = 0; r < 8; ++r)
    #pragma unroll
    for (int c = 0; c < 8; ++c) {
      const float inter = (float)acc[r][c];
      sims[r][c] = -inter / (si[r] + sj[c] - inter);
    }

  // direct: row i0+r, cols j0..j0+7 (2 float4, coalesced across lj)
  #pragma unroll
  for (int r = 0; r < 8; ++r) {
    floatx4 v0, v1;
    #pragma unroll
    for (int c = 0; c < 4; ++c) { v0[c] = sims[r][c]; v1[c] = sims[r][c + 4]; }
    float* dst = &out[(size_t)(i0 + r) * B_ROWS + j0];
    __builtin_nontemporal_store(v0, (floatx4*)dst);
    __builtin_nontemporal_store(v1, (floatx4*)(dst + 4));
  }
  // mirror: row j0+c, cols i0..i0+7 (2 float4, coalesced across li)
  #pragma unroll
  for (int c = 0; c < 8; ++c) {
    floatx4 v0, v1;
    #pragma unroll
    for (int r = 0; r < 4; ++r) { v0[r] = sims[r][c]; v1[r] = sims[r + 4][c]; }
    float* dst = &out[(size_t)(j0 + c) * B_ROWS + i0];
    __builtin_nontemporal_store(v0, (floatx4*)dst);
    __builtin_nontemporal_store(v1, (floatx4*)(dst + 4));
  }
}

// ---------------- launcher ---------------------------------------------------
extern "C" void kernel_launch(void* const* d_in, const int* in_sizes, int n_in,
                              void* d_out, int out_size, void* d_ws, size_t ws_size,
                              hipStream_t stream) {
  const int* features = (const int*)d_in[0];
  float* out = (float*)d_out;
  uint32_t* bits2 = (uint32_t*)d_ws;                      // 4 MB word-major
  float* sizes = (float*)((char*)d_ws + (size_t)NW * B_ROWS * 4);  // +16 KB

  presence_kernel<<<NG, 256, 0, stream>>>(features, bits2, sizes);
  inter_kernel<<<528, 256, 0, stream>>>(bits2, sizes, out);
}